// Round 2
// baseline (459.530 us; speedup 1.0000x reference)
//
#include <hip/hip_runtime.h>

// SCF GRU layer: T=40, B=128, N=64, H=48, BN=8192, DIN=52.
// Round 2: single barrier/step (double-buffered LDS), software-pipelined
// global x-loads, packed fp32 FMA (v_pk_fma_f32), G0 folded into k_gru,
// prep kernels fused. 2 launches total.

#define T_STEPS 40
#define BB      128
#define NN      64
#define HH      48
#define BN      8192
#define G3      144   // 3*H

typedef float v2f __attribute__((ext_vector_type(2)));

__device__ __forceinline__ v2f pkfma(v2f a, v2f b, v2f c) {
    return __builtin_elementwise_fma(a, b, c);
}
__device__ __forceinline__ float sigmoid_(float x) {
    return __builtin_amdgcn_rcpf(1.0f + __expf(-x));
}

// ---------------- prep: img mean (blocks 0..4095) + loc sums (blocks 4096..5375)
__global__ __launch_bounds__(256) void k_prep(const float* __restrict__ f_img,
                                              const float* __restrict__ path,
                                              float* __restrict__ img_out,
                                              float* __restrict__ S) {
    if (blockIdx.x < 4096) {
        const int bc = blockIdx.x;  // b*32 + c
        const float4* p = reinterpret_cast<const float4*>(f_img + (size_t)bc * 6400);
        float s = 0.0f;
        for (int i = threadIdx.x; i < 1600; i += 256) {
            float4 v = p[i];
            s += v.x + v.y + v.z + v.w;
        }
        for (int off = 32; off > 0; off >>= 1) s += __shfl_down(s, off, 64);
        __shared__ float red[4];
        const int wid = threadIdx.x >> 6, lane = threadIdx.x & 63;
        if (lane == 0) red[wid] = s;
        __syncthreads();
        if (threadIdx.x == 0)
            img_out[bc] = (red[0] + red[1] + red[2] + red[3]) * (1.0f / 6400.0f);
    } else {
        // 1280 blocks x 4 waves: one (t,b) pair per wave. p = t*128 + b.
        const int p = (blockIdx.x - 4096) * 4 + (threadIdx.x >> 6);
        const int lane = threadIdx.x & 63;
        if (p < T_STEPS * BB) {
            const float2 v = reinterpret_cast<const float2*>(path)[(size_t)p * 64 + lane];
            float sx = v.x, sy = v.y;
            for (int off = 32; off > 0; off >>= 1) {
                sx += __shfl_down(sx, off, 64);
                sy += __shfl_down(sy, off, 64);
            }
            if (lane == 0) { S[p * 2] = sx; S[p * 2 + 1] = sy; }
        }
    }
}

// ---------------- main recurrence ----------------
// Block = 192 threads = 2 rows x 96. q = j*2 + half; shfl_xor(1) pairs halves.
__global__ __launch_bounds__(192, 3) void k_gru(const float* __restrict__ path,
                                                const float* __restrict__ f_vel,
                                                const float* __restrict__ W_ih,
                                                const float* __restrict__ W_hh,
                                                const float* __restrict__ b_ih,
                                                const float* __restrict__ b_hh,
                                                const float* __restrict__ img,
                                                const float* __restrict__ S,
                                                float* __restrict__ out) {
    const int tid  = threadIdx.x;
    const int r    = tid / 96;
    const int q    = tid % 96;
    const int j    = q >> 1;
    const int half = q & 1;
    const int row  = blockIdx.x * 2 + r;
    const int b    = row >> 6;

    __shared__ __align__(16) float sh[2][2][HH];   // [buf][row][j]
    __shared__ __align__(16) float sx[2][2][20];   // [buf][row][loc2,rel2,vel16]

    // ---- weights into registers (packed pairs) ----
    v2f wihr[5], wihz[5], wihn[5];
    v2f whhr[12], whhz[12], whhn[12];
    {
        const v2f* wr = reinterpret_cast<const v2f*>(W_ih + (j)      * 52 + half * 10);
        const v2f* wz = reinterpret_cast<const v2f*>(W_ih + (48 + j) * 52 + half * 10);
        const v2f* wn = reinterpret_cast<const v2f*>(W_ih + (96 + j) * 52 + half * 10);
#pragma unroll
        for (int p = 0; p < 5; ++p) { wihr[p] = wr[p]; wihz[p] = wz[p]; wihn[p] = wn[p]; }
    }
    {
        const v2f* wr = reinterpret_cast<const v2f*>(W_hh + (j)      * 48 + half * 24);
        const v2f* wz = reinterpret_cast<const v2f*>(W_hh + (48 + j) * 48 + half * 24);
        const v2f* wn = reinterpret_cast<const v2f*>(W_hh + (96 + j) * 48 + half * 24);
#pragma unroll
        for (int p = 0; p < 12; ++p) { whhr[p] = wr[p]; whhz[p] = wz[p]; whhn[p] = wn[p]; }
    }

    // ---- G0 = b_ih + img_feat . W_ih[:,20:52]  (time-invariant gi part) ----
    float g0r, g0z, g0n;
    {
        const float4* im4 = reinterpret_cast<const float4*>(img + b * 32);
        const float4* wr4 = reinterpret_cast<const float4*>(W_ih + (j)      * 52 + 20);
        const float4* wz4 = reinterpret_cast<const float4*>(W_ih + (48 + j) * 52 + 20);
        const float4* wn4 = reinterpret_cast<const float4*>(W_ih + (96 + j) * 52 + 20);
        float ar = b_ih[j], az = b_ih[48 + j], an = b_ih[96 + j];
#pragma unroll
        for (int c = 0; c < 8; ++c) {
            const float4 iv = im4[c];
            const float4 a = wr4[c], z4 = wz4[c], n4 = wn4[c];
            ar = fmaf(iv.x, a.x, fmaf(iv.y, a.y, fmaf(iv.z, a.z, fmaf(iv.w, a.w, ar))));
            az = fmaf(iv.x, z4.x, fmaf(iv.y, z4.y, fmaf(iv.z, z4.z, fmaf(iv.w, z4.w, az))));
            an = fmaf(iv.x, n4.x, fmaf(iv.y, n4.y, fmaf(iv.z, n4.z, fmaf(iv.w, n4.w, an))));
        }
        g0r = ar; g0z = az; g0n = an;
    }
    const float bhr = b_hh[j], bhz = b_hh[48 + j], bhn = b_hh[96 + j];

    // ---- preload x[0] and h0 into buffer 0 ----
    float4 vreg;           // f_vel chunk (threads q<4)
    float2 preg, sreg;     // path + S (thread q==4)
    if (q < 4)  vreg = reinterpret_cast<const float4*>(f_vel + (size_t)row * 16)[q];
    if (q == 4) {
        preg = reinterpret_cast<const float2*>(path)[row];
        sreg = reinterpret_cast<const float2*>(S)[b];
    }
    if (half == 0) sh[0][r][j] = 0.0f;
    if (q < 4) reinterpret_cast<float4*>(&sx[0][r][4])[q] = vreg;
    if (q == 4) {
        sx[0][r][0] = preg.x;
        sx[0][r][1] = preg.y;
        sx[0][r][2] = (sreg.x - 64.0f * preg.x) * (1.0f / 63.0f);
        sx[0][r][3] = (sreg.y - 64.0f * preg.y) * (1.0f / 63.0f);
    }
    __syncthreads();

    int buf = 0;
    for (int t = 0; t < T_STEPS; ++t) {
        // ---- issue prefetch for t+1 (lands in registers during compute) ----
        const int tn = (t + 1 < T_STEPS) ? t + 1 : t;
        if (q < 4)  vreg = reinterpret_cast<const float4*>(f_vel + ((size_t)tn * BN + row) * 16)[q];
        if (q == 4) {
            preg = reinterpret_cast<const float2*>(path)[(size_t)tn * BN + row];
            sreg = reinterpret_cast<const float2*>(S)[tn * BB + b];
        }

        // ---- gates: packed FMA over this thread's K-half ----
        const v2f* sx2 = reinterpret_cast<const v2f*>(&sx[buf][r][0]);
        const v2f* sh2 = reinterpret_cast<const v2f*>(&sh[buf][r][0]);
        v2f ar = {0.f, 0.f}, az = {0.f, 0.f}, ani = {0.f, 0.f}, anh = {0.f, 0.f};
#pragma unroll
        for (int p = 0; p < 5; ++p) {
            const v2f xv = sx2[half * 5 + p];
            ar  = pkfma(xv, wihr[p], ar);
            az  = pkfma(xv, wihz[p], az);
            ani = pkfma(xv, wihn[p], ani);
        }
#pragma unroll
        for (int p = 0; p < 12; ++p) {
            const v2f hv = sh2[half * 12 + p];
            ar  = pkfma(hv, whhr[p], ar);
            az  = pkfma(hv, whhz[p], az);
            anh = pkfma(hv, whhn[p], anh);
        }
        float sr  = ar.x + ar.y;   sr  += __shfl_xor(sr, 1, 64);
        float szv = az.x + az.y;   szv += __shfl_xor(szv, 1, 64);
        float sni = ani.x + ani.y; sni += __shfl_xor(sni, 1, 64);
        float snh = anh.x + anh.y; snh += __shfl_xor(snh, 1, 64);

        const float rg = sigmoid_(sr + g0r + bhr);
        const float zg = sigmoid_(szv + g0z + bhz);
        float a = (sni + g0n) + rg * (snh + bhn);
        a = fminf(fmaxf(a, -15.0f), 15.0f);
        const float e = __expf(-2.0f * a);
        const float cand = (1.0f - e) * __builtin_amdgcn_rcpf(1.0f + e);
        const float hp = sh[buf][r][j];
        const float hn = zg * (hp - cand) + cand;

        // ---- write next state + staged x into the OTHER buffer ----
        const int nb = buf ^ 1;
        if (half == 0) sh[nb][r][j] = hn;
        else {
            out[((size_t)t * BN + row) * HH + j] = hn;
            if (t == T_STEPS - 1)
                out[(size_t)T_STEPS * BN * HH + (size_t)row * HH + j] = hn;
        }
        if (q < 4) reinterpret_cast<float4*>(&sx[nb][r][4])[q] = vreg;
        if (q == 4) {
            sx[nb][r][0] = preg.x;
            sx[nb][r][1] = preg.y;
            sx[nb][r][2] = (sreg.x - 64.0f * preg.x) * (1.0f / 63.0f);
            sx[nb][r][3] = (sreg.y - 64.0f * preg.y) * (1.0f / 63.0f);
        }
        __syncthreads();   // single barrier per step
        buf = nb;
    }
}

extern "C" void kernel_launch(void* const* d_in, const int* in_sizes, int n_in,
                              void* d_out, int out_size, void* d_ws, size_t ws_size,
                              hipStream_t stream) {
    const float* path  = (const float*)d_in[0];
    const float* f_vel = (const float*)d_in[1];
    const float* f_img = (const float*)d_in[2];
    const float* W_ih  = (const float*)d_in[3];
    const float* W_hh  = (const float*)d_in[4];
    const float* b_ih  = (const float*)d_in[5];
    const float* b_hh  = (const float*)d_in[6];
    float* out = (float*)d_out;

    float* ws  = (float*)d_ws;
    float* img = ws;            // 4096 floats
    float* S   = ws + 4096;     // 10240 floats

    hipLaunchKernelGGL(k_prep, dim3(4096 + 1280), dim3(256), 0, stream,
                       f_img, path, img, S);
    hipLaunchKernelGGL(k_gru, dim3(BN / 2), dim3(192), 0, stream,
                       path, f_vel, W_ih, W_hh, b_ih, b_hh, img, S, out);
}